// Round 11
// baseline (497.041 us; speedup 1.0000x reference)
//
#include <hip/hip_runtime.h>
#include <cstdint>
#include <cstddef>

// Problem constants (reference: M=8192, IN=4096, OUT=4096)
#define M_DIM 8192
#define K_DIM 4096
#define N_DIM 4096

// GEMM tile geometry
#define BM 256
#define BN 256
#define BK 64
#define NT (K_DIM / BK)  // 64 K-tiles

typedef unsigned short u16;
typedef __bf16 bf16x8 __attribute__((ext_vector_type(8)));
typedef u16 u16x8 __attribute__((ext_vector_type(8)));
typedef float f32x4 __attribute__((ext_vector_type(4)));

// fp32 -> bf16 round-to-nearest-even (inputs are finite normals; no NaN path)
__device__ __forceinline__ u16 f2bf_rne(float f) {
  uint32_t u = __builtin_bit_cast(uint32_t, f);
  return (u16)((u + 0x7FFFu + ((u >> 16) & 1u)) >> 16);
}
// small int -> bf16 (exact for |i| <= 8)
__device__ __forceinline__ u16 i2bf(int i) {
  return (u16)(__builtin_bit_cast(uint32_t, (float)i) >> 16);
}

#define XBLKS 16384  // M*K/8/256 blocks for the x-conversion half
#define WBLKS 8192   // N*(K/2)/4/256 blocks for the weight-dequant half

// ---- Fused prep (round-6 proven): x fp32->bf16, int4 -> bf16 int weights --
__global__ __launch_bounds__(256) void prep(const float* __restrict__ x,
                                            const int* __restrict__ wp,
                                            u16* __restrict__ xb,
                                            u16* __restrict__ wb) {
  const int b = blockIdx.x;
  if (b < XBLKS) {
    size_t t = (size_t)b * 256 + threadIdx.x;
    const float4* xp = (const float4*)x;
    float4 a = xp[2 * t];
    float4 c = xp[2 * t + 1];
    u16x8 r;
    r[0] = f2bf_rne(a.x); r[1] = f2bf_rne(a.y); r[2] = f2bf_rne(a.z); r[3] = f2bf_rne(a.w);
    r[4] = f2bf_rne(c.x); r[5] = f2bf_rne(c.y); r[6] = f2bf_rne(c.z); r[7] = f2bf_rne(c.w);
    ((u16x8*)xb)[t] = r;
  } else {
    size_t t = (size_t)(b - XBLKS) * 256 + threadIdx.x;
    int4 p = ((const int4*)wp)[t];
    u16x8 r;
    int v;
    v = p.x ^ 0x88; r[0] = i2bf((v << 28) >> 28); r[1] = i2bf((v << 24) >> 28);
    v = p.y ^ 0x88; r[2] = i2bf((v << 28) >> 28); r[3] = i2bf((v << 24) >> 28);
    v = p.z ^ 0x88; r[4] = i2bf((v << 28) >> 28); r[5] = i2bf((v << 24) >> 28);
    v = p.w ^ 0x88; r[6] = i2bf((v << 28) >> 28); r[7] = i2bf((v << 24) >> 28);
    ((u16x8*)wb)[t] = r;
  }
}

// ---- bf16 gemm_bt: 256x256 tile, 16x16x32 MFMA, PHASE-PACED pipeline ------
// C[m][n] = (sum_k A[m][k]*B[n][k]) * scale[n] + bias[n]
//
// ROUND-11: revert round-10's 32x32 MFMA (its 32-row x 2-chunk read pattern
// bank-conflicts 2.5e7/dispatch under this swizzle; the 16-row x 4-chunk
// 16x16 pattern measures 0). On top of the verified round-6 kernel, add
// m201-style PHASE PACING: each of the 4 per-tile 16-MFMA clusters is wrapped
// in barrier pairs {reads; stage; s_barrier; lgkmcnt(0); setprio; MFMA;
// setprio; s_barrier}. Mechanism: a wave issues its cluster, crosses the
// post-cluster barrier immediately (no acc-result wait), and issues the next
// phase's ds_reads UNDER its draining MFMAs, while block-wide lockstep keeps
// the LDS and MFMA pipes alternating across all 8 waves. (Round-5's failure
// used sched_barrier fences, not barrier pairs — different structure.)
//
// SYNC SKELETON (round-5/6 proven raceless, counted vmcnt):
// K-tile = 4 half-tiles (A0/A1 rows 0-127/128-255, B0/B1), each 128x64x2B =
// 16 KiB = 2 global_load_lds/thread (512 thr). A0 has 3 slots (T%3), A1/B0/B1
// have 2 (T&1) -> 144 KiB. Per iter T: stage A0(T+1) (its slot held A0(T-2),
// reads long retired -> safe pre-barrier) -> s_waitcnt vmcnt(2) (waits the 8
// oldest = all of tile T; never drains in main loop) -> cert s_barrier
// (tile T landed everywhere AND tile T-1 reads retired -> (T+1)-parity
// buffers free) -> 4 paced phases with A1/B0/B1(T+1) stages one per phase.
// Tail peeled with one vmcnt(0). Phase barriers are pure added ordering on
// this skeleton: barrier count is uniform (no divergent control), and the
// only pre-cert write (stA0) targets slot (T+1)%3, disjoint from all buffers
// read in tile T's phases. No deadlock, no new hazards.
//
// Swizzle (verified SQ_LDS_BANK_CONFLICT==0 on this read pattern): LDS row =
// 64 u16 = 128 B = 32 banks. Thread tid stages global 16B-chunk
// ((tid&7) ^ (srow&7)) into linear LDS slot tid&7 (global_load_lds needs
// linear dest, rule 21); readers address slot chunk ^ (lrow&7). Staged rows
// step by 64 == 0 mod 8 -> key invariant.
__global__ __launch_bounds__(512, 2) void gemm_bt_w4a16(
    const u16* __restrict__ A,      // [M_DIM, K_DIM] bf16 bits
    const u16* __restrict__ B,      // [N_DIM, K_DIM] bf16 bits (integer weights)
    const float* __restrict__ scales,
    const float* __restrict__ bias,
    float* __restrict__ C) {
  __shared__ u16 sA0[3][128 * 64];  // 48 KiB, slot = T%3
  __shared__ u16 sA1[2][128 * 64];  // 32 KiB, slot = T&1
  __shared__ u16 sB0[2][128 * 64];  // 32 KiB
  __shared__ u16 sB1[2][128 * 64];  // 32 KiB   total 144 KiB

  const int tid = threadIdx.x;
  const int lane = tid & 63;
  const int wave = tid >> 6;          // 0..7
  const int m0 = blockIdx.y * BM;
  const int n0 = blockIdx.x * BN;

  const int wm = (wave >> 2) * 128;   // 0 or 128   (2 M-waves)
  const int wn = (wave & 3) * 64;     // 0,64,128,192 (4 N-waves)
  const int lrow = lane & 15;         // row within a 16x16 frag
  const int quad = lane >> 4;         // k-chunk selector; m-subrow for C/D
  const int brw0 = wn & 64;           // B row base within its half

  f32x4 acc[8][4] = {};

  // Staging map: thread tid covers half-rows srow and srow+64 (2 loads),
  // linear chunk slot tid&7; global source chunk XOR-swizzled by srow&7.
  const int srow = tid >> 3;                    // 0..63
  const int schunk = ((tid & 7) ^ (srow & 7)) * 8;
  const u16* ga = A + (size_t)(m0 + srow) * K_DIM + schunk;  // A half0 row srow
  const u16* gb = B + (size_t)(n0 + srow) * K_DIM + schunk;
  const int dst0 = tid * 16;                    // LDS byte offset; +8192 for row+64

#define GLDS(gp, lp)                                                      \
  __builtin_amdgcn_global_load_lds(                                       \
      (const __attribute__((address_space(1))) void*)(gp),                \
      (__attribute__((address_space(3))) void*)(lp), 16, 0, 0)

  // Stage one half-tile (2 loads: rows srow and srow+64 of the half).
  auto stA0 = [&](int slot, int T) {
    const u16* g = ga + (size_t)T * BK;
    char* d = (char*)sA0[slot] + dst0;
    GLDS(g, d);
    GLDS(g + (size_t)64 * K_DIM, d + 8192);
  };
  auto stA1 = [&](int b, int T) {
    const u16* g = ga + (size_t)128 * K_DIM + (size_t)T * BK;
    char* d = (char*)sA1[b] + dst0;
    GLDS(g, d);
    GLDS(g + (size_t)64 * K_DIM, d + 8192);
  };
  auto stB0 = [&](int b, int T) {
    const u16* g = gb + (size_t)T * BK;
    char* d = (char*)sB0[b] + dst0;
    GLDS(g, d);
    GLDS(g + (size_t)64 * K_DIM, d + 8192);
  };
  auto stB1 = [&](int b, int T) {
    const u16* g = gb + (size_t)128 * K_DIM + (size_t)T * BK;
    char* d = (char*)sB1[b] + dst0;
    GLDS(g, d);
    GLDS(g + (size_t)64 * K_DIM, d + 8192);
  };

  struct frag4 { u16x8 v[4]; };

  // Phase boundary before MFMA: all waves rendezvous, then wait own reads.
#define PHASE_GATE()                                       \
  __builtin_amdgcn_s_barrier();                            \
  asm volatile("s_waitcnt lgkmcnt(0)" ::: "memory");       \
  __builtin_amdgcn_sched_barrier(0)

#define CLUSTER16(fa, fb, base)                                           \
  __builtin_amdgcn_s_setprio(1);                                          \
  _Pragma("unroll")                                                       \
  for (int i = 0; i < 4; ++i)                                             \
    _Pragma("unroll")                                                     \
    for (int j = 0; j < 4; ++j)                                           \
      acc[(base) + i][j] = __builtin_amdgcn_mfma_f32_16x16x32_bf16(       \
          __builtin_bit_cast(bf16x8, (fa).v[i]),                          \
          __builtin_bit_cast(bf16x8, (fb).v[j]), acc[(base) + i][j],      \
          0, 0, 0);                                                       \
  __builtin_amdgcn_s_setprio(0)

  // Prologue: tile 0 fully staged (8 loads).
  stA0(0, 0); stA1(0, 0); stB0(0, 0); stB1(0, 0);

  int a0slot = 0;  // slot of tile T's A0
#pragma unroll 1
  for (int T = 0; T < NT; ++T) {
    const int buf = T & 1;
    const int nbuf = buf ^ 1;
    const bool more = (T + 1 < NT);
    int a0next = a0slot + 1; if (a0next == 3) a0next = 0;

    if (more) {
      stA0(a0next, T + 1);                       // counted-wait enabler
      asm volatile("s_waitcnt vmcnt(2)" ::: "memory");  // tile T (8 oldest) landed
    } else {
      asm volatile("s_waitcnt vmcnt(0)" ::: "memory");  // peeled tail drain
    }
    __builtin_amdgcn_s_barrier();                // cert: young loads stay in flight
    __builtin_amdgcn_sched_barrier(0);           // anti-hoist fence

    const u16* aH = (wave < 4) ? sA0[a0slot] : sA1[buf];
    const u16* bH = (wn < 128) ? sB0[buf] : sB1[buf];

    const int kc0 = ((0 * 4 + quad) ^ (lrow & 7)) * 8;
    const int kc1 = ((1 * 4 + quad) ^ (lrow & 7)) * 8;

    auto ldA = [&](int ih, int kc) {
      frag4 f;
#pragma unroll
      for (int i = 0; i < 4; ++i)
        f.v[i] = *(const u16x8*)(aH + (ih * 64 + i * 16 + lrow) * BK + kc);
      return f;
    };
    auto ldB = [&](int kc) {
      frag4 f;
#pragma unroll
      for (int j = 0; j < 4; ++j)
        f.v[j] = *(const u16x8*)(bH + (brw0 + j * 16 + lrow) * BK + kc);
      return f;
    };

    // ---- Phase 0: reads overlap tile T-1's P3 MFMA drain ----
    frag4 bfr0 = ldB(kc0);
    frag4 afA = ldA(0, kc0);
    if (more) stA1(nbuf, T + 1);
    PHASE_GATE();
    CLUSTER16(afA, bfr0, 0);
    __builtin_amdgcn_s_barrier();                // release: reads of P1 go under P0 drain

    // ---- Phase 1 ----
    frag4 afB = ldA(1, kc0);
    if (more) stB0(nbuf, T + 1);
    PHASE_GATE();
    CLUSTER16(afB, bfr0, 4);
    __builtin_amdgcn_s_barrier();

    // ---- Phase 2 ----
    frag4 afA2 = ldA(0, kc1);
    frag4 bfr1 = ldB(kc1);
    if (more) stB1(nbuf, T + 1);
    PHASE_GATE();
    CLUSTER16(afA2, bfr1, 0);
    __builtin_amdgcn_s_barrier();

    // ---- Phase 3 (no trailing barrier: next is the cert barrier) ----
    frag4 afB2 = ldA(1, kc1);
    PHASE_GATE();
    CLUSTER16(afB2, bfr1, 4);

    __builtin_amdgcn_sched_barrier(0);           // anti-sink fence (tile ends)
    a0slot = a0next;
  }

  // Epilogue: C/D layout col = lane&15 (n), row = quad*4 + reg (m). Apply
  // per-output-row scale + bias here (keeps MFMA inputs exact integers).
#pragma unroll
  for (int j = 0; j < 4; ++j) {
    const int n = n0 + wn + j * 16 + lrow;
    const float sc = scales[n];
    const float bi = bias[n];
#pragma unroll
    for (int i = 0; i < 8; ++i) {
      const int m = m0 + wm + i * 16 + quad * 4;
      float* cp = &C[(size_t)m * N_DIM + n];
#pragma unroll
      for (int r = 0; r < 4; ++r)
        cp[(size_t)r * N_DIM] = acc[i][j][r] * sc + bi;
    }
  }
#undef GLDS
#undef PHASE_GATE
#undef CLUSTER16
}

// ---------------- Fallback (ws too small): fp32 direct, correct but slow ----
__global__ __launch_bounds__(256) void fallback_w4a16(
    const float* __restrict__ x, const int* __restrict__ wp,
    const float* __restrict__ scales, const float* __restrict__ bias,
    float* __restrict__ out) {
  const int n = blockIdx.x * 256 + threadIdx.x;
  const int m = blockIdx.y;
  const float* xr = x + (size_t)m * K_DIM;
  const int* wr = wp + (size_t)n * (K_DIM / 2);
  float acc = 0.f;
  for (int j = 0; j < K_DIM / 2; ++j) {
    int w = wr[j] ^ 0x88;
    float lo = (float)((w << 28) >> 28);
    float hi = (float)((w << 24) >> 28);
    acc += xr[2 * j] * lo + xr[2 * j + 1] * hi;
  }
  out[(size_t)m * N_DIM + n] = acc * scales[n] + bias[n];
}

extern "C" void kernel_launch(void* const* d_in, const int* in_sizes, int n_in,
                              void* d_out, int out_size, void* d_ws, size_t ws_size,
                              hipStream_t stream) {
  const float* x = (const float*)d_in[0];
  const int* wp = (const int*)d_in[1];
  const float* sc = (const float*)d_in[2];
  const float* bi = (const float*)d_in[3];
  float* out = (float*)d_out;

  const size_t xb_elems = (size_t)M_DIM * K_DIM;           // 64 MiB as u16
  const size_t wb_elems = (size_t)N_DIM * K_DIM;           // 32 MiB as u16
  const size_t need = (xb_elems + wb_elems) * sizeof(u16); // 100,663,296 B

  if (ws_size >= need) {
    u16* xb = (u16*)d_ws;
    u16* wb = xb + xb_elems;
    prep<<<XBLKS + WBLKS, 256, 0, stream>>>(x, wp, xb, wb);
    gemm_bt_w4a16<<<dim3(N_DIM / BN, M_DIM / BM), 512, 0, stream>>>(xb, wb, sc, bi, out);
  } else {
    fallback_w4a16<<<dim3(N_DIM / 256, M_DIM), 256, 0, stream>>>(x, wp, sc, bi, out);
  }
}